// Round 2
// baseline (918.346 us; speedup 1.0000x reference)
//
#include <hip/hip_runtime.h>
#include <stdint.h>

static constexpr int THREADS = 256;
static constexpr int NXCD = 8;

typedef int   vint4   __attribute__((ext_vector_type(4)));
typedef float vfloat4 __attribute__((ext_vector_type(4)));

__device__ __forceinline__ int get_xcc_id() {
  unsigned v;
  asm("s_getreg_b32 %0, hwreg(HW_REG_XCC_ID)" : "=s"(v));
  return (int)(v & 0xfu);
}

// Flagless (workgroup-scope) fp32 atomic add: no sc0/sc1 bits -> serviced at
// the issuing XCD's local L2 instead of the memory-side coherence point.
// Atomic across all waves on the SAME XCD only — safe because each XCD gets
// its own private replica of the scatter target.
__device__ __forceinline__ void l2_atomic_add(float* p, float v) {
  asm volatile("global_atomic_add_f32 %0, %1, off"
               :: "v"((uint64_t)(uintptr_t)p), "v"(v));
}

// ---------------------------------------------------------------------------
// Kernel 1: zero replicas + accumulators + output.
// ---------------------------------------------------------------------------
__global__ __launch_bounds__(THREADS) void kkt_zero(
    float* __restrict__ buf, int total_floats,
    double* __restrict__ acc, float* __restrict__ out) {
  int idx = blockIdx.x * blockDim.x + threadIdx.x;
  int stride = gridDim.x * blockDim.x;
  vfloat4* b4 = (vfloat4*)buf;
  int n4 = total_floats >> 2;
  for (int i = idx; i < n4; i += stride) b4[i] = (vfloat4)(0.0f);
  for (int i = (n4 << 2) + idx; i < total_floats; i += stride) buf[i] = 0.0f;
  if (idx < 4) acc[idx] = 0.0;
  if (idx == 0) out[0] = 0.0f;
}

// ---------------------------------------------------------------------------
// Kernel 2: fused edge pass. XCD_REP=true -> per-XCD replica + L2-local
// atomics; false -> single buffer + agent-scope unsafeAtomicAdd (fallback).
// Nontemporal edge loads keep x/lam resident in L2 for the gathers.
// ---------------------------------------------------------------------------
template <bool XCD_REP>
__global__ __launch_bounds__(THREADS) void kkt_edges(
    const int* __restrict__ rows, const int* __restrict__ cols,
    const float* __restrict__ attr,
    const float* __restrict__ x, const float* __restrict__ lam,
    float* __restrict__ AxR, float* __restrict__ ATlamR,
    int sum_m, int sum_n, int E) {
  float* Ax;
  float* ATl;
  if (XCD_REP) {
    const int xcc = get_xcc_id();
    Ax  = AxR    + (size_t)xcc * (size_t)sum_m;
    ATl = ATlamR + (size_t)xcc * (size_t)sum_n;
  } else {
    Ax  = AxR;
    ATl = ATlamR;
  }
  int idx = blockIdx.x * blockDim.x + threadIdx.x;
  int stride = gridDim.x * blockDim.x;
  int e4 = E >> 2;
  const vint4*   rows4 = (const vint4*)rows;
  const vint4*   cols4 = (const vint4*)cols;
  const vfloat4* attr4 = (const vfloat4*)attr;
  for (int i = idx; i < e4; i += stride) {
    vint4   r = __builtin_nontemporal_load(rows4 + i);
    vint4   c = __builtin_nontemporal_load(cols4 + i);
    vfloat4 a = __builtin_nontemporal_load(attr4 + i);
    float xc0 = x[c.x], xc1 = x[c.y], xc2 = x[c.z], xc3 = x[c.w];
    float lr0 = lam[r.x], lr1 = lam[r.y], lr2 = lam[r.z], lr3 = lam[r.w];
    if (XCD_REP) {
      l2_atomic_add(&Ax[r.x], a.x * xc0);
      l2_atomic_add(&Ax[r.y], a.y * xc1);
      l2_atomic_add(&Ax[r.z], a.z * xc2);
      l2_atomic_add(&Ax[r.w], a.w * xc3);
      l2_atomic_add(&ATl[c.x], a.x * lr0);
      l2_atomic_add(&ATl[c.y], a.y * lr1);
      l2_atomic_add(&ATl[c.z], a.z * lr2);
      l2_atomic_add(&ATl[c.w], a.w * lr3);
    } else {
      unsafeAtomicAdd(&Ax[r.x], a.x * xc0);
      unsafeAtomicAdd(&Ax[r.y], a.y * xc1);
      unsafeAtomicAdd(&Ax[r.z], a.z * xc2);
      unsafeAtomicAdd(&Ax[r.w], a.w * xc3);
      unsafeAtomicAdd(&ATl[c.x], a.x * lr0);
      unsafeAtomicAdd(&ATl[c.y], a.y * lr1);
      unsafeAtomicAdd(&ATl[c.z], a.z * lr2);
      unsafeAtomicAdd(&ATl[c.w], a.w * lr3);
    }
  }
  for (int i = (e4 << 2) + idx; i < E; i += stride) {
    int rr = rows[i], cc = cols[i];
    float a = attr[i];
    if (XCD_REP) {
      l2_atomic_add(&Ax[rr], a * x[cc]);
      l2_atomic_add(&ATl[cc], a * lam[rr]);
    } else {
      unsafeAtomicAdd(&Ax[rr], a * x[cc]);
      unsafeAtomicAdd(&ATl[cc], a * lam[rr]);
    }
  }
  // Drain our inline-asm atomics (compiler doesn't track them) before endpgm.
  asm volatile("s_waitcnt vmcnt(0)" ::: "memory");
}

// ---------------------------------------------------------------------------
// Kernel 3: sum replicas + loss vectors + reduction.
// seg_mean_sq(v).sum() == sum(v*v)/per under uniform segment sizes.
// fp64 accumulation for the global sums.
// ---------------------------------------------------------------------------
template <int NR>
__global__ __launch_bounds__(THREADS) void kkt_loss(
    const float* __restrict__ AxR, const float* __restrict__ ATlamR,
    const float* __restrict__ bcat, const float* __restrict__ ccat,
    const float* __restrict__ lam, double* __restrict__ acc,
    int sum_m, int sum_n) {
  int idx = blockIdx.x * blockDim.x + threadIdx.x;
  int stride = gridDim.x * blockDim.x;
  double pr = 0.0, du = 0.0, st = 0.0, cs = 0.0;
  for (int i = idx; i < sum_m; i += stride) {
    float ax = 0.0f;
#pragma unroll
    for (int r = 0; r < NR; ++r) ax += AxR[(size_t)r * sum_m + i];
    float d  = ax - bcat[i];
    float li = lam[i];
    float p    = d > 0.0f ? d : 0.0f;
    float u    = li < 0.0f ? -li : 0.0f;
    float comp = li * d;
    pr += (double)p * p;
    du += (double)u * u;
    cs += (double)comp * comp;
  }
  for (int i = idx; i < sum_n; i += stride) {
    float at = 0.0f;
#pragma unroll
    for (int r = 0; r < NR; ++r) at += ATlamR[(size_t)r * sum_n + i];
    float s = at + ccat[i];
    st += (double)s * s;
  }
  for (int off = 32; off > 0; off >>= 1) {
    pr += __shfl_down(pr, off);
    du += __shfl_down(du, off);
    st += __shfl_down(st, off);
    cs += __shfl_down(cs, off);
  }
  if ((threadIdx.x & 63) == 0) {
    unsafeAtomicAdd(&acc[0], pr);
    unsafeAtomicAdd(&acc[1], du);
    unsafeAtomicAdd(&acc[2], st);
    unsafeAtomicAdd(&acc[3], cs);
  }
}

// ---------------------------------------------------------------------------
// Kernel 4: weights + per-count scaling + /B.
// ---------------------------------------------------------------------------
__global__ void kkt_finalize(const double* __restrict__ acc,
                             const int* __restrict__ Bp,
                             const int* __restrict__ mp,
                             const int* __restrict__ np_,
                             float* __restrict__ out) {
  double m = (double)mp[0];
  double n = (double)np_[0];
  double B = (double)Bp[0];
  double total =
      (0.1 * (acc[0] + acc[1]) / m + 0.6 * acc[2] / n + 0.2 * acc[3] / m) / B;
  out[0] = (float)total;
}

extern "C" void kernel_launch(void* const* d_in, const int* in_sizes, int n_in,
                              void* d_out, int out_size, void* d_ws, size_t ws_size,
                              hipStream_t stream) {
  const float* x    = (const float*)d_in[0];
  const float* lam  = (const float*)d_in[1];
  const int*   rows = (const int*)d_in[2];
  const int*   cols = (const int*)d_in[3];
  const float* attr = (const float*)d_in[4];
  const float* bcat = (const float*)d_in[5];
  const float* ccat = (const float*)d_in[6];
  const int*   Bp   = (const int*)d_in[7];
  const int*   mp   = (const int*)d_in[8];
  const int*   np_  = (const int*)d_in[9];

  const int sum_n = in_sizes[0];
  const int sum_m = in_sizes[1];
  const int E     = in_sizes[2];

  char*   ws  = (char*)d_ws;
  double* acc = (double*)ws;
  float*  buf = (float*)(ws + 64);   // replicas: [NR][sum_m] then [NR][sum_n]
  float*  out = (float*)d_out;

  const size_t need_rep = 64 + (size_t)NXCD * (size_t)(sum_m + sum_n) * 4;
  const bool rep = ws_size >= need_rep;
  const int NR = rep ? NXCD : 1;

  float* AxR    = buf;
  float* ATlamR = buf + (size_t)NR * sum_m;

  int total_floats = NR * (sum_m + sum_n);
  int zb = ((total_floats >> 2) + THREADS - 1) / THREADS;
  if (zb > 2048) zb = 2048;
  kkt_zero<<<zb, THREADS, 0, stream>>>(buf, total_floats, acc, out);

  int eb = ((E >> 2) + THREADS - 1) / THREADS;
  if (eb > 2048) eb = 2048;
  if (rep) {
    kkt_edges<true><<<eb, THREADS, 0, stream>>>(rows, cols, attr, x, lam,
                                                AxR, ATlamR, sum_m, sum_n, E);
  } else {
    kkt_edges<false><<<eb, THREADS, 0, stream>>>(rows, cols, attr, x, lam,
                                                 AxR, ATlamR, sum_m, sum_n, E);
  }

  int lw = sum_m > sum_n ? sum_m : sum_n;
  int lb = (lw + THREADS - 1) / THREADS;
  if (lb > 1024) lb = 1024;
  if (rep) {
    kkt_loss<NXCD><<<lb, THREADS, 0, stream>>>(AxR, ATlamR, bcat, ccat, lam,
                                               acc, sum_m, sum_n);
  } else {
    kkt_loss<1><<<lb, THREADS, 0, stream>>>(AxR, ATlamR, bcat, ccat, lam,
                                            acc, sum_m, sum_n);
  }

  kkt_finalize<<<1, 1, 0, stream>>>(acc, Bp, mp, np_, out);
}

// Round 3
// 252.317 us; speedup vs baseline: 3.6396x; 3.6396x over previous
//
#include <hip/hip_runtime.h>
#include <stdint.h>

static constexpr int THREADS      = 256;
static constexpr int SCAN_THREADS = 1024;
static constexpr int CM  = 16384;          // rows per chunk
static constexpr int CN  = 16384;          // cols per chunk
static constexpr int CSZ = CM + CN;        // 32768 floats = 128 KB LDS
static constexpr int MAX_REP = 32;

typedef int   vint4   __attribute__((ext_vector_type(4)));
typedef float vfloat4 __attribute__((ext_vector_type(4)));

// ---------------------------------------------------------------------------
// init: zero the 4 fp64 accumulators + output scalar.
// ---------------------------------------------------------------------------
__global__ void kkt_init(double* __restrict__ acc, float* __restrict__ out) {
  int t = threadIdx.x;
  if (t < 4) acc[t] = 0.0;
  if (t == 0) out[0] = 0.0f;
}

// ---------------------------------------------------------------------------
// scan: block (p = chunk, r = edge slice). Accumulate matching edges into a
// 128 KB LDS chunk-pair with LDS atomics (ds_add_f32), flush non-atomically
// to partial[(p*REP + r)*CSZ .. +CSZ). ZERO global atomics.
// ---------------------------------------------------------------------------
__global__ __launch_bounds__(SCAN_THREADS) void kkt_scan(
    const int* __restrict__ rows, const int* __restrict__ cols,
    const float* __restrict__ attr,
    const float* __restrict__ x, const float* __restrict__ lam,
    float* __restrict__ partial, int E, int REP) {
  __shared__ float lds[CSZ];
  const int p = blockIdx.x / REP;
  const int r = blockIdx.x % REP;
  const int baseM = p * CM;
  const int baseN = p * CN;

  vfloat4* l4 = (vfloat4*)lds;
  for (int i = threadIdx.x; i < CSZ / 4; i += SCAN_THREADS) l4[i] = (vfloat4)(0.0f);
  __syncthreads();

  // edge slice [e0, e1), e0 multiple of 4
  long per = (((long)E + REP - 1) / REP + 3) & ~3L;
  long e0 = per * r;       if (e0 > E) e0 = E;
  long e1 = e0 + per;      if (e1 > E) e1 = E;
  int  n4 = (int)((e1 - e0) >> 2);

  const vint4*   rows4 = (const vint4*)(rows + e0);
  const vint4*   cols4 = (const vint4*)(cols + e0);
  const vfloat4* attr4 = (const vfloat4*)(attr + e0);

#define EDGE_ACC(RR, CC, AA)                                              \
  do {                                                                    \
    unsigned mm = (unsigned)((RR) - baseM);                               \
    if (mm < (unsigned)CM) unsafeAtomicAdd(&lds[mm], (AA) * x[(CC)]);     \
    unsigned nn = (unsigned)((CC) - baseN);                               \
    if (nn < (unsigned)CN) unsafeAtomicAdd(&lds[CM + nn], (AA) * lam[(RR)]); \
  } while (0)

  for (int i = threadIdx.x; i < n4; i += SCAN_THREADS) {
    vint4   rr = rows4[i];
    vint4   cc = cols4[i];
    vfloat4 aa = attr4[i];
    EDGE_ACC(rr.x, cc.x, aa.x);
    EDGE_ACC(rr.y, cc.y, aa.y);
    EDGE_ACC(rr.z, cc.z, aa.z);
    EDGE_ACC(rr.w, cc.w, aa.w);
  }
  // scalar tail (only if E % 4 != 0, last slice)
  for (long i = e0 + ((long)n4 << 2) + threadIdx.x; i < e1; i += SCAN_THREADS) {
    int rr = rows[i], cc = cols[i];
    float aa = attr[i];
    EDGE_ACC(rr, cc, aa);
  }
#undef EDGE_ACC

  __syncthreads();
  // non-atomic coalesced flush of the private replica
  vfloat4* d4 = (vfloat4*)(partial + (size_t)(p * REP + r) * CSZ);
  for (int i = threadIdx.x; i < CSZ / 4; i += SCAN_THREADS) d4[i] = l4[i];
}

// ---------------------------------------------------------------------------
// reduce + loss: sum the REP replicas per element, then loss math.
// seg_mean_sq(v).sum() == sum(v*v)/per under uniform segment sizes.
// fp64 accumulation; ~4 fp64 atomics per wave total.
// ---------------------------------------------------------------------------
__global__ __launch_bounds__(THREADS) void kkt_reduce_loss(
    const float* __restrict__ partial,
    const float* __restrict__ bcat, const float* __restrict__ ccat,
    const float* __restrict__ lam, double* __restrict__ acc,
    int sum_m, int sum_n, int REP) {
  int idx = blockIdx.x * blockDim.x + threadIdx.x;
  int stride = gridDim.x * blockDim.x;
  double pr = 0.0, du = 0.0, st = 0.0, cs = 0.0;
  for (int i = idx; i < sum_m; i += stride) {
    int p = i / CM, j = i - p * CM;
    const float* base = partial + (size_t)(p * REP) * CSZ + j;
    float ax = 0.0f;
    for (int rr = 0; rr < REP; ++rr) ax += base[(size_t)rr * CSZ];
    float d  = ax - bcat[i];
    float li = lam[i];
    float pp   = d > 0.0f ? d : 0.0f;
    float u    = li < 0.0f ? -li : 0.0f;
    float comp = li * d;
    pr += (double)pp * pp;
    du += (double)u * u;
    cs += (double)comp * comp;
  }
  for (int i = idx; i < sum_n; i += stride) {
    int p = i / CN, j = i - p * CN;
    const float* base = partial + (size_t)(p * REP) * CSZ + CM + j;
    float at = 0.0f;
    for (int rr = 0; rr < REP; ++rr) at += base[(size_t)rr * CSZ];
    float s = at + ccat[i];
    st += (double)s * s;
  }
  for (int off = 32; off > 0; off >>= 1) {
    pr += __shfl_down(pr, off);
    du += __shfl_down(du, off);
    st += __shfl_down(st, off);
    cs += __shfl_down(cs, off);
  }
  if ((threadIdx.x & 63) == 0) {
    unsafeAtomicAdd(&acc[0], pr);
    unsafeAtomicAdd(&acc[1], du);
    unsafeAtomicAdd(&acc[2], st);
    unsafeAtomicAdd(&acc[3], cs);
  }
}

// ---------------------------------------------------------------------------
// fallback (ws too small): direct agent-scope atomics (R1 path).
// ---------------------------------------------------------------------------
__global__ __launch_bounds__(THREADS) void kkt_zero_fb(
    float* __restrict__ buf, int n, double* __restrict__ acc,
    float* __restrict__ out) {
  int idx = blockIdx.x * blockDim.x + threadIdx.x;
  int stride = gridDim.x * blockDim.x;
  for (int i = idx; i < n; i += stride) buf[i] = 0.0f;
  if (idx < 4) acc[idx] = 0.0;
  if (idx == 0) out[0] = 0.0f;
}

__global__ __launch_bounds__(THREADS) void kkt_edges_fb(
    const int* __restrict__ rows, const int* __restrict__ cols,
    const float* __restrict__ attr,
    const float* __restrict__ x, const float* __restrict__ lam,
    float* __restrict__ Ax, float* __restrict__ ATlam, int E) {
  int idx = blockIdx.x * blockDim.x + threadIdx.x;
  int stride = gridDim.x * blockDim.x;
  for (int i = idx; i < E; i += stride) {
    int r = rows[i], c = cols[i];
    float a = attr[i];
    unsafeAtomicAdd(&Ax[r], a * x[c]);
    unsafeAtomicAdd(&ATlam[c], a * lam[r]);
  }
}

__global__ __launch_bounds__(THREADS) void kkt_loss_fb(
    const float* __restrict__ Ax, const float* __restrict__ ATlam,
    const float* __restrict__ bcat, const float* __restrict__ ccat,
    const float* __restrict__ lam, double* __restrict__ acc,
    int sum_m, int sum_n) {
  int idx = blockIdx.x * blockDim.x + threadIdx.x;
  int stride = gridDim.x * blockDim.x;
  double pr = 0.0, du = 0.0, st = 0.0, cs = 0.0;
  for (int i = idx; i < sum_m; i += stride) {
    float d  = Ax[i] - bcat[i];
    float li = lam[i];
    float pp = d > 0.0f ? d : 0.0f;
    float u  = li < 0.0f ? -li : 0.0f;
    float comp = li * d;
    pr += (double)pp * pp;
    du += (double)u * u;
    cs += (double)comp * comp;
  }
  for (int i = idx; i < sum_n; i += stride) {
    float s = ATlam[i] + ccat[i];
    st += (double)s * s;
  }
  for (int off = 32; off > 0; off >>= 1) {
    pr += __shfl_down(pr, off);
    du += __shfl_down(du, off);
    st += __shfl_down(st, off);
    cs += __shfl_down(cs, off);
  }
  if ((threadIdx.x & 63) == 0) {
    unsafeAtomicAdd(&acc[0], pr);
    unsafeAtomicAdd(&acc[1], du);
    unsafeAtomicAdd(&acc[2], st);
    unsafeAtomicAdd(&acc[3], cs);
  }
}

// ---------------------------------------------------------------------------
// finalize
// ---------------------------------------------------------------------------
__global__ void kkt_finalize(const double* __restrict__ acc,
                             const int* __restrict__ Bp,
                             const int* __restrict__ mp,
                             const int* __restrict__ np_,
                             float* __restrict__ out) {
  double m = (double)mp[0];
  double n = (double)np_[0];
  double B = (double)Bp[0];
  double total =
      (0.1 * (acc[0] + acc[1]) / m + 0.6 * acc[2] / n + 0.2 * acc[3] / m) / B;
  out[0] = (float)total;
}

extern "C" void kernel_launch(void* const* d_in, const int* in_sizes, int n_in,
                              void* d_out, int out_size, void* d_ws, size_t ws_size,
                              hipStream_t stream) {
  const float* x    = (const float*)d_in[0];
  const float* lam  = (const float*)d_in[1];
  const int*   rows = (const int*)d_in[2];
  const int*   cols = (const int*)d_in[3];
  const float* attr = (const float*)d_in[4];
  const float* bcat = (const float*)d_in[5];
  const float* ccat = (const float*)d_in[6];
  const int*   Bp   = (const int*)d_in[7];
  const int*   mp   = (const int*)d_in[8];
  const int*   np_  = (const int*)d_in[9];

  const int sum_n = in_sizes[0];
  const int sum_m = in_sizes[1];
  const int E     = in_sizes[2];

  char*   ws  = (char*)d_ws;
  double* acc = (double*)ws;
  float*  buf = (float*)(ws + 64);
  float*  out = (float*)d_out;

  const int NPm = (sum_m + CM - 1) / CM;
  const int NPn = (sum_n + CN - 1) / CN;
  const int NP  = NPm > NPn ? NPm : NPn;

  size_t avail = ws_size > 64 ? ws_size - 64 : 0;
  int REP = (int)(avail / ((size_t)NP * CSZ * sizeof(float)));
  if (REP > MAX_REP) REP = MAX_REP;

  if (REP >= 1) {
    kkt_init<<<1, 64, 0, stream>>>(acc, out);
    kkt_scan<<<NP * REP, SCAN_THREADS, 0, stream>>>(rows, cols, attr, x, lam,
                                                    buf, E, REP);
    int lw = sum_m > sum_n ? sum_m : sum_n;
    int lb = (lw + THREADS - 1) / THREADS;
    if (lb > 1024) lb = 1024;
    kkt_reduce_loss<<<lb, THREADS, 0, stream>>>(buf, bcat, ccat, lam, acc,
                                                sum_m, sum_n, REP);
  } else {
    // tiny-ws fallback: direct atomics
    float* Ax    = buf;
    float* ATlam = buf + sum_m;
    int zb = (sum_m + sum_n + THREADS - 1) / THREADS;
    if (zb > 2048) zb = 2048;
    kkt_zero_fb<<<zb, THREADS, 0, stream>>>(Ax, sum_m + sum_n, acc, out);
    int eb = (E + THREADS - 1) / THREADS;
    if (eb > 2048) eb = 2048;
    kkt_edges_fb<<<eb, THREADS, 0, stream>>>(rows, cols, attr, x, lam, Ax,
                                             ATlam, E);
    int lw = sum_m > sum_n ? sum_m : sum_n;
    int lb = (lw + THREADS - 1) / THREADS;
    if (lb > 1024) lb = 1024;
    kkt_loss_fb<<<lb, THREADS, 0, stream>>>(Ax, ATlam, bcat, ccat, lam, acc,
                                            sum_m, sum_n);
  }
  kkt_finalize<<<1, 1, 0, stream>>>(acc, Bp, mp, np_, out);
}